// Round 12
// baseline (1082.427 us; speedup 1.0000x reference)
//
#include <hip/hip_runtime.h>

// Problem constants
#define BATCH 4
#define SEQ   2048
#define DIM   1024
#define MTOT  (BATCH * SEQ)   // 8192

typedef __bf16 bf16x8 __attribute__((ext_vector_type(8)));
typedef float  f32x4  __attribute__((ext_vector_type(4)));

#define VMCNT(N) asm volatile("s_waitcnt vmcnt(" #N ")" ::: "memory")

// Async global->LDS, 16B per lane (HW: wave-uniform base + lane*16).
__device__ __forceinline__ void gl_lds16(const __bf16* g, __bf16* l) {
    __builtin_amdgcn_global_load_lds(
        (const __attribute__((address_space(1))) void*)g,
        (__attribute__((address_space(3))) void*)l,
        16, 0, 0);
}

// ---------------------------------------------------------------------------
// K0: fused fp32 -> bf16 conversion for x, Wq, Wk, Wv in ONE launch.
// Blocks 5632..5639 zero the row-sum accumulator (8192 f32).
__global__ __launch_bounds__(256) void cvt_all_kernel(
    const float* __restrict__ x,  const float* __restrict__ w0,
    const float* __restrict__ w1, const float* __restrict__ w2,
    __bf16* __restrict__ xd, __bf16* __restrict__ d0,
    __bf16* __restrict__ d1, __bf16* __restrict__ d2,
    float* __restrict__ sums)
{
    const int bid = blockIdx.x;
    if (bid >= 5632) {
        const int i = ((bid - 5632) * 256 + threadIdx.x) * 4;
        *(float4*)(sums + i) = (float4){0.f, 0.f, 0.f, 0.f};
        return;
    }
    const float* s;
    __bf16* d;
    int base;
    if (bid < 4096)      { s = x;  d = xd; base = bid; }
    else if (bid < 4608) { s = w0; d = d0; base = bid - 4096; }
    else if (bid < 5120) { s = w1; d = d1; base = bid - 4608; }
    else                 { s = w2; d = d2; base = bid - 5120; }
    const int i = (base * 256 + threadIdx.x) * 8;
    const float4 a = *(const float4*)(s + i);
    const float4 b = *(const float4*)(s + i + 4);
    bf16x8 o;
    o[0] = (__bf16)a.x; o[1] = (__bf16)a.y; o[2] = (__bf16)a.z; o[3] = (__bf16)a.w;
    o[4] = (__bf16)b.x; o[5] = (__bf16)b.y; o[6] = (__bf16)b.z; o[7] = (__bf16)b.w;
    *(bf16x8*)(d + i) = o;
}

// ---------------------------------------------------------------------------
// unit128 (BK=64, SINGLE-buffered): C[128][128] = A[128][K]·B[128][K]^T,
// 256 threads (4 waves), wave grid 2M x 2N (wave 64x64, acc[4][4], legacy
// fragment mapping: rows wm + i*16 + quad*4 + r, cols wn + j*16 + ln15).
// LDS 32 KiB: A[128][64] @0 + B[128][64] @8192 elems (ONE buffer) ->
// 5 blocks/CU at 256 threads (20 waves). TLP across 5 independent barrier
// domains fills the per-block drain stalls (m114): MFMA demand 5x622 cyc per
// round >> per-block serial path, so the CU approaches MFMA-bound.
// Per K-tile: reads(16 b128) + 32 MFMA -> syncthreads (reads consumed) ->
// STG(T+1) + vmcnt(0) drain -> syncthreads (staging sealed for all waves).
// Rotation swizzle (mod 8, proven r2..r9, 327K residual conflicts):
// LDS[r][pc] holds G[r][(pc - r) & 7] (8-elem chunks); inverse rotation on
// the gl_lds global source column, forward rotation on the ds_read address;
// ksub1 address = ksub0 ^ 32 elems (chunk+4 mod 8).
__device__ __forceinline__ void unit128(
    const __bf16* __restrict__ Ab, size_t lda,
    const __bf16* __restrict__ Bb, size_t ldb,
    int nt, __bf16* smem, f32x4 (&acc)[4][4])
{
    const int tid  = threadIdx.x;           // 0..255
    const int lane = tid & 63;
    const int ln15 = lane & 15;
    const int quad = lane >> 4;
    const int wave = tid >> 6;              // 0..3
    const int wm   = (wave >> 1) << 6;      // 0 / 64
    const int wn   = (wave & 1) << 6;       // 0 / 64

    // forward-rotated read column (elements): chunk = (quad + row&7) & 7
    const int cq = (((quad << 3) + ((ln15 & 7) << 3)) & 63);

    int aoff[4], boff[4];
#pragma unroll
    for (int i = 0; i < 4; ++i) aoff[i] = (wm + i * 16 + ln15) * 64 + cq;
#pragma unroll
    for (int j = 0; j < 4; ++j) boff[j] = 8192 + (wn + j * 16 + ln15) * 64 + cq;

#pragma unroll
    for (int i = 0; i < 4; ++i)
#pragma unroll
        for (int j = 0; j < 4; ++j) acc[i][j] = (f32x4){0.f, 0.f, 0.f, 0.f};

    // Stage tile t: thread covers chunks c = tid + it*256 (row=c>>3, pc=c&7);
    // source chunk = (pc - row) & 7 (inverse rotation); LDS dest linear.
#define STG(t) do {                                                           \
    const int k0_ = (t) << 6;                                                 \
    _Pragma("unroll") for (int it_ = 0; it_ < 4; ++it_) {                     \
        const int c_ = tid + (it_ << 8);                                      \
        const int r_ = c_ >> 3;                                               \
        const int cc_ = ((((c_ & 7) + 8) - (r_ & 7)) & 7) << 3;               \
        gl_lds16(Ab + (size_t)r_ * lda + k0_ + cc_, smem + c_ * 8);           \
        gl_lds16(Bb + (size_t)r_ * ldb + k0_ + cc_, smem + 8192 + c_ * 8);    \
    } } while (0)

    bf16x8 aF[4][2], bF[4][2];

    STG(0);
    VMCNT(0);                                // tile 0 sealed
    __syncthreads();

    for (int T = 0; T < nt; ++T) {
#pragma unroll
        for (int i = 0; i < 4; ++i) {
            aF[i][0] = *(const bf16x8*)(smem + aoff[i]);
            aF[i][1] = *(const bf16x8*)(smem + (aoff[i] ^ 32));
        }
#pragma unroll
        for (int j = 0; j < 4; ++j) {
            bF[j][0] = *(const bf16x8*)(smem + boff[j]);
            bF[j][1] = *(const bf16x8*)(smem + (boff[j] ^ 32));
        }
        __builtin_amdgcn_s_setprio(1);
#pragma unroll
        for (int ks = 0; ks < 2; ++ks)
#pragma unroll
            for (int i = 0; i < 4; ++i)
#pragma unroll
                for (int j = 0; j < 4; ++j)
                    acc[i][j] = __builtin_amdgcn_mfma_f32_16x16x32_bf16(
                        aF[i][ks], bF[j][ks], acc[i][j], 0, 0, 0);
        __builtin_amdgcn_s_setprio(0);
        __syncthreads();                     // all waves' reads consumed
        if (T + 1 < nt) {
            STG(T + 1);                      // overwrite the single buffer
            VMCNT(0);                        // sealed (this wave's 8 stages)
            __syncthreads();                 // sealed for ALL waves
        }
    }
#undef STG
}

// ---------------------------------------------------------------------------
// Epilogue (256-thr, 4-wave, legacy mapping): C-tile -> LDS scratch (32x136)
// -> coalesced bf16x8 stores. expMask: store exp(val*scale), causal-masked on
// diag tiles. sums!=nullptr: per-row sums of stored (bf16-rounded) values.
__device__ __forceinline__ void store_tile_bf16(
    f32x4 (&acc)[4][4], __bf16* scratch, bool transpose, float scale,
    __bf16* dst, size_t ldo, size_t r0, size_t c0,
    bool expMask = false, bool diag = false, float* sums = nullptr)
{
    const int tid  = threadIdx.x;
    const int lane = tid & 63;
    const int wave = tid >> 6;
    const int wm = (wave >> 1) << 6, wn = (wave & 1) << 6;
    const int quad = lane >> 4;
    const int ln15 = lane & 15;

#pragma unroll
    for (int p = 0; p < 4; ++p) {
        __syncthreads();
        if (!transpose) {
            if (wm == ((p >> 1) << 6)) {
#pragma unroll
                for (int ih = 0; ih < 2; ++ih) {
                    const int i = ((p & 1) << 1) + ih;
                    const int lr = ih * 16 + quad * 4;
#pragma unroll
                    for (int r = 0; r < 4; ++r) {
                        const int lm = wm + ((p & 1) << 5) + lr + r;
                        float ps = 0.f;
#pragma unroll
                        for (int j = 0; j < 4; ++j) {
                            const int ln = wn + j * 16 + ln15;
                            float v = acc[i][j][r] * scale;
                            if (expMask) {
                                v = (!diag || ln <= lm) ? __expf(v) : 0.f;
                            }
                            const __bf16 vb = (__bf16)v;
                            scratch[(lr + r) * 136 + ln] = vb;
                            ps += (float)vb;
                        }
                        if (sums) {
#pragma unroll
                            for (int off = 1; off < 16; off <<= 1)
                                ps += __shfl_xor(ps, off);
                            if (ln15 == 0)
                                atomicAdd(&sums[r0 + (p << 5) + lr + r], ps);
                        }
                    }
                }
            }
        } else {
            if (wn == ((p >> 1) << 6)) {
#pragma unroll
                for (int jh = 0; jh < 2; ++jh) {
                    const int j = ((p & 1) << 1) + jh;
                    const int lr = jh * 16 + ln15;
#pragma unroll
                    for (int i = 0; i < 4; ++i)
#pragma unroll
                        for (int r = 0; r < 4; ++r)
                            scratch[lr * 136 + wm + i * 16 + quad * 4 + r] =
                                (__bf16)(acc[i][j][r] * scale);
                }
            }
        }
        __syncthreads();
#pragma unroll
        for (int it = 0; it < 2; ++it) {
            const int g   = tid + (it << 8);
            const int row = g >> 4;
            const int col = (g & 15) << 3;
            *(bf16x8*)(dst + (r0 + p * 32 + row) * ldo + c0 + col) =
                *(const bf16x8*)(scratch + row * 136 + col);
        }
    }
}

// ---------------------------------------------------------------------------
// K1: QKV — 1536 single-unit blocks (one 128x128 unit each; 64 x-panels x 24
// W-units). Wall = contiguous [3072][1024] bf16. 5 blocks/CU -> capacity
// 1280 resident + 256 trailing. Bijective XCD swizzle (1536 = 8*192): XCD c
// owns x-panels [8c, 8c+8) (2 MB, L2-resident).
__global__ __launch_bounds__(256, 5) void qkv_kernel(
    const __bf16* __restrict__ x,
    const __bf16* __restrict__ Wall,
    __bf16* __restrict__ Q, __bf16* __restrict__ Kb, __bf16* __restrict__ Vt)
{
    __shared__ __bf16 smem[16384];   // 32 KiB

    const int L  = blockIdx.x;
    const int g  = (L & 7) * 192 + (L >> 3);  // 0..1535
    const int m0 = (g / 24) << 7;             // 64 m-panels of 128 rows
    const int u  = g % 24;                    // W-unit over Wall's 3072 rows

    const __bf16* Ab = x + (size_t)m0 * DIM;

    f32x4 acc[4][4];
    unit128(Ab, DIM, Wall + (size_t)(u << 7) * DIM, DIM, DIM / 64, smem, acc);

    const int z  = u >> 3;                    // 0=Q, 1=K, 2=V
    const int n0 = (u & 7) << 7;
    if (z == 0) {
        store_tile_bf16(acc, smem, false, 1.f, Q,  DIM, m0, n0);
    } else if (z == 1) {
        store_tile_bf16(acc, smem, false, 1.f, Kb, DIM, m0, n0);
    } else {
        const size_t b  = (size_t)(m0 >> 11);
        const int  ms0  = m0 & (SEQ - 1);
        store_tile_bf16(acc, smem, true, 1.f,
                        Vt + b * (size_t)DIM * SEQ, SEQ, n0, ms0);
    }
}

// ---------------------------------------------------------------------------
// K2: Sc[b] = exp( Q[b]·K[b]^T / 32 ), UNNORMALIZED, causal-masked on the
// diagonal tile; accumulates per-row sums. Tri-packed 544 blocks; XCD
// swizzle. At 5 blocks/CU all 544 are co-resident -> single round.
__global__ __launch_bounds__(256, 5) void scores_kernel(
    const __bf16* __restrict__ Q, const __bf16* __restrict__ Kb,
    __bf16* __restrict__ Sc, float* __restrict__ sums)
{
    __shared__ __bf16 smem[16384];   // 32 KiB

    const int L = blockIdx.x;
    const int g = (L & 7) * 68 + (L >> 3);   // 0..543
    const int b = g / 136;
    const int t = g - b * 136;
    int i = (int)((sqrtf(8.f * t + 1.f) - 1.f) * 0.5f);
    while ((i + 1) * (i + 2) / 2 <= t) ++i;
    while (i * (i + 1) / 2 > t) --i;
    const int j = t - i * (i + 1) / 2;

    const __bf16* A  = Q  + (size_t)b * SEQ * DIM + (size_t)(i << 7) * DIM;
    const __bf16* Bm = Kb + (size_t)b * SEQ * DIM + (size_t)(j << 7) * DIM;

    f32x4 acc[4][4];
    unit128(A, DIM, Bm, DIM, DIM / 64, smem, acc);

    store_tile_bf16(acc, smem, false, 0.03125f,   // 1/sqrt(1024)
                    Sc + (size_t)b * SEQ * SEQ, SEQ,
                    (size_t)(i << 7), (size_t)(j << 7),
                    /*expMask=*/true, /*diag=*/(i == j),
                    sums + (size_t)b * SEQ);
}

// ---------------------------------------------------------------------------
// K4: O[b] = (P'[b] @ V[b]) / rowsum. 512 blocks, all co-resident at 5/CU:
// unit = 128 P-rows (ti) x 128 V-cols (dj), K = (ti+1)*128 to the causal
// diagonal (tiles above diagonal never read). XCD c owns batch c>>1 with
// alternating-ti set, ti-descending (LPT).
__global__ __launch_bounds__(256, 5) void pv_kernel(
    const __bf16* __restrict__ P, const __bf16* __restrict__ Vt,
    const float* __restrict__ sums, float* __restrict__ out)
{
    __shared__ __bf16 smem[16384];   // 32 KiB

    const int L   = blockIdx.x;
    const int c   = L & 7;
    const int idx = L >> 3;                        // 0..63
    const int b   = c >> 1;
    const int ti  = 15 - (c & 1) - ((idx >> 3) << 1);  // {15,13,..,1}/{14,..,0}
    const int dj  = idx & 7;

    const __bf16* A  = P  + (size_t)b * SEQ * SEQ + (size_t)(ti << 7) * SEQ;
    const __bf16* Bm = Vt + (size_t)b * DIM * SEQ + (size_t)(dj << 7) * SEQ;

    f32x4 acc[4][4];
    unit128(A, SEQ, Bm, SEQ, (ti + 1) * 2, smem, acc);

    const int tid  = threadIdx.x;
    const int lane = tid & 63;
    const int ln15 = lane & 15;
    const int quad = lane >> 4;
    const int wave = tid >> 6;
    const int wm   = (wave >> 1) << 6;
    const int wn   = (wave & 1) << 6;

#pragma unroll
    for (int i = 0; i < 4; ++i)
#pragma unroll
        for (int r = 0; r < 4; ++r) {
            const int m = (ti << 7) + wm + i * 16 + quad * 4 + r;
            const float s = sums[(b << 11) + m];
            float* orow = out + ((size_t)b * SEQ + m) * DIM + (dj << 7);
#pragma unroll
            for (int j = 0; j < 4; ++j)
                orow[wn + j * 16 + ln15] = acc[i][j][r] / s;
        }
}

// ---------------------------------------------------------------------------
extern "C" void kernel_launch(void* const* d_in, const int* in_sizes, int n_in,
                              void* d_out, int out_size, void* d_ws, size_t ws_size,
                              hipStream_t stream) {
    const float* x  = (const float*)d_in[0];   // fp32 per reference
    const float* Wq = (const float*)d_in[1];
    const float* Wk = (const float*)d_in[2];
    const float* Wv = (const float*)d_in[3];
    float* out = (float*)d_out;                // fp32 output (reference dtype)

    char* ws = (char*)d_ws;
    __bf16* Q  = (__bf16*)(ws);                       // 16 MB
    __bf16* Kb = (__bf16*)(ws + (16ull << 20));       // 16 MB
    __bf16* Vt = (__bf16*)(ws + (32ull << 20));       // 16 MB
    __bf16* Sc = (__bf16*)(ws + (48ull << 20));       // 32 MB bf16 exp-scores
    __bf16* Wqb = (__bf16*)(ws + (80ull << 20));      // 2 MB (Wall rows 0..1023)
    __bf16* Wkb = (__bf16*)(ws + (82ull << 20));      // 2 MB (Wall rows 1024..2047)
    __bf16* Wvb = (__bf16*)(ws + (84ull << 20));      // 2 MB (Wall rows 2048..3071)
    float*  sums = (float*)(ws + (86ull << 20));      // 32 KB row sums
    // bf16 x copy lives in d_out (32 MB fp32): dead before pv writes out.
    __bf16* xb  = (__bf16*)d_out;                     // 16 MB

    cvt_all_kernel<<<dim3(5640), 256, 0, stream>>>(x, Wq, Wk, Wv, xb, Wqb, Wkb, Wvb,
                                                   sums);

    qkv_kernel    <<<dim3(1536), 256, 0, stream>>>(xb, Wqb, Q, Kb, Vt);
    scores_kernel <<<dim3(544),  256, 0, stream>>>(Q, Kb, Sc, sums);
    pv_kernel     <<<dim3(512),  256, 0, stream>>>(Sc, Vt, sums, out);
}

// Round 13
// 383.959 us; speedup vs baseline: 2.8191x; 2.8191x over previous
//
#include <hip/hip_runtime.h>

// Problem constants
#define BATCH 4
#define SEQ   2048
#define DIM   1024
#define MTOT  (BATCH * SEQ)   // 8192

typedef __bf16 bf16x8 __attribute__((ext_vector_type(8)));
typedef float  f32x4  __attribute__((ext_vector_type(4)));

#define VMCNT(N) asm volatile("s_waitcnt vmcnt(" #N ")" ::: "memory")

// Async global->LDS, 16B per lane (HW: wave-uniform base + lane*16).
__device__ __forceinline__ void gl_lds16(const __bf16* g, __bf16* l) {
    __builtin_amdgcn_global_load_lds(
        (const __attribute__((address_space(1))) void*)g,
        (__attribute__((address_space(3))) void*)l,
        16, 0, 0);
}

// ---------------------------------------------------------------------------
// K0: fused fp32 -> bf16 conversion for x, Wq, Wk, Wv in ONE launch.
// Blocks 5632..5639 zero the row-sum accumulator (8192 f32).
__global__ __launch_bounds__(256) void cvt_all_kernel(
    const float* __restrict__ x,  const float* __restrict__ w0,
    const float* __restrict__ w1, const float* __restrict__ w2,
    __bf16* __restrict__ xd, __bf16* __restrict__ d0,
    __bf16* __restrict__ d1, __bf16* __restrict__ d2,
    float* __restrict__ sums)
{
    const int bid = blockIdx.x;
    if (bid >= 5632) {
        const int i = ((bid - 5632) * 256 + threadIdx.x) * 4;
        *(float4*)(sums + i) = (float4){0.f, 0.f, 0.f, 0.f};
        return;
    }
    const float* s;
    __bf16* d;
    int base;
    if (bid < 4096)      { s = x;  d = xd; base = bid; }
    else if (bid < 4608) { s = w0; d = d0; base = bid - 4096; }
    else if (bid < 5120) { s = w1; d = d1; base = bid - 4608; }
    else                 { s = w2; d = d2; base = bid - 5120; }
    const int i = (base * 256 + threadIdx.x) * 8;
    const float4 a = *(const float4*)(s + i);
    const float4 b = *(const float4*)(s + i + 4);
    bf16x8 o;
    o[0] = (__bf16)a.x; o[1] = (__bf16)a.y; o[2] = (__bf16)a.z; o[3] = (__bf16)a.w;
    o[4] = (__bf16)b.x; o[5] = (__bf16)b.y; o[6] = (__bf16)b.z; o[7] = (__bf16)b.w;
    *(bf16x8*)(d + i) = o;
}

// ---------------------------------------------------------------------------
// unit128 (BK=64, SINGLE-buffered): C[128][128] = A[128][K]·B[128][K]^T,
// 256 threads (4 waves), wave grid 2M x 2N (wave 64x64, acc[4][4], legacy
// fragment mapping: rows wm + i*16 + quad*4 + r, cols wn + j*16 + ln15).
// LDS 32 KiB: A[128][64] @0 + B[128][64] @8192 elems (ONE buffer).
// Occupancy: __launch_bounds__(256, 4) -> VGPR cap 128 >= ~112 needed
// (r12 LESSON: (256,5) caps at 102 -> acc spilled to scratch, VGPR 48,
// 2.2 GB scratch traffic, 10x regression). 4 blocks/CU = 4 independent
// barrier domains overlapping MFMA with staging (m114).
// Per K-tile: reads(16 b128) + 32 MFMA -> syncthreads (reads consumed) ->
// STG(T+1) + vmcnt(0) drain -> syncthreads (staging sealed for all waves).
// Rotation swizzle (mod 8, proven r2..r9, 327K residual conflicts):
// LDS[r][pc] holds G[r][(pc - r) & 7] (8-elem chunks); inverse rotation on
// the gl_lds global source column, forward rotation on the ds_read address;
// ksub1 address = ksub0 ^ 32 elems (chunk+4 mod 8).
__device__ __forceinline__ void unit128(
    const __bf16* __restrict__ Ab, size_t lda,
    const __bf16* __restrict__ Bb, size_t ldb,
    int nt, __bf16* smem, f32x4 (&acc)[4][4])
{
    const int tid  = threadIdx.x;           // 0..255
    const int lane = tid & 63;
    const int ln15 = lane & 15;
    const int quad = lane >> 4;
    const int wave = tid >> 6;              // 0..3
    const int wm   = (wave >> 1) << 6;      // 0 / 64
    const int wn   = (wave & 1) << 6;       // 0 / 64

    // forward-rotated read column (elements): chunk = (quad + row&7) & 7
    const int cq = (((quad << 3) + ((ln15 & 7) << 3)) & 63);

    int aoff[4], boff[4];
#pragma unroll
    for (int i = 0; i < 4; ++i) aoff[i] = (wm + i * 16 + ln15) * 64 + cq;
#pragma unroll
    for (int j = 0; j < 4; ++j) boff[j] = 8192 + (wn + j * 16 + ln15) * 64 + cq;

#pragma unroll
    for (int i = 0; i < 4; ++i)
#pragma unroll
        for (int j = 0; j < 4; ++j) acc[i][j] = (f32x4){0.f, 0.f, 0.f, 0.f};

    // Stage tile t: thread covers chunks c = tid + it*256 (row=c>>3, pc=c&7);
    // source chunk = (pc - row) & 7 (inverse rotation); LDS dest linear.
#define STG(t) do {                                                           \
    const int k0_ = (t) << 6;                                                 \
    _Pragma("unroll") for (int it_ = 0; it_ < 4; ++it_) {                     \
        const int c_ = tid + (it_ << 8);                                      \
        const int r_ = c_ >> 3;                                               \
        const int cc_ = ((((c_ & 7) + 8) - (r_ & 7)) & 7) << 3;               \
        gl_lds16(Ab + (size_t)r_ * lda + k0_ + cc_, smem + c_ * 8);           \
        gl_lds16(Bb + (size_t)r_ * ldb + k0_ + cc_, smem + 8192 + c_ * 8);    \
    } } while (0)

    bf16x8 aF[4][2], bF[4][2];

    STG(0);
    VMCNT(0);                                // tile 0 sealed
    __syncthreads();

    for (int T = 0; T < nt; ++T) {
#pragma unroll
        for (int i = 0; i < 4; ++i) {
            aF[i][0] = *(const bf16x8*)(smem + aoff[i]);
            aF[i][1] = *(const bf16x8*)(smem + (aoff[i] ^ 32));
        }
#pragma unroll
        for (int j = 0; j < 4; ++j) {
            bF[j][0] = *(const bf16x8*)(smem + boff[j]);
            bF[j][1] = *(const bf16x8*)(smem + (boff[j] ^ 32));
        }
        __builtin_amdgcn_s_setprio(1);
#pragma unroll
        for (int ks = 0; ks < 2; ++ks)
#pragma unroll
            for (int i = 0; i < 4; ++i)
#pragma unroll
                for (int j = 0; j < 4; ++j)
                    acc[i][j] = __builtin_amdgcn_mfma_f32_16x16x32_bf16(
                        aF[i][ks], bF[j][ks], acc[i][j], 0, 0, 0);
        __builtin_amdgcn_s_setprio(0);
        __syncthreads();                     // all waves' reads consumed
        if (T + 1 < nt) {
            STG(T + 1);                      // overwrite the single buffer
            VMCNT(0);                        // sealed (this wave's 8 stages)
            __syncthreads();                 // sealed for ALL waves
        }
    }
#undef STG
}

// ---------------------------------------------------------------------------
// Epilogue (256-thr, 4-wave, legacy mapping): C-tile -> LDS scratch (32x136)
// -> coalesced bf16x8 stores. expMask: store exp(val*scale), causal-masked on
// diag tiles. sums!=nullptr: per-row sums of stored (bf16-rounded) values.
__device__ __forceinline__ void store_tile_bf16(
    f32x4 (&acc)[4][4], __bf16* scratch, bool transpose, float scale,
    __bf16* dst, size_t ldo, size_t r0, size_t c0,
    bool expMask = false, bool diag = false, float* sums = nullptr)
{
    const int tid  = threadIdx.x;
    const int lane = tid & 63;
    const int wave = tid >> 6;
    const int wm = (wave >> 1) << 6, wn = (wave & 1) << 6;
    const int quad = lane >> 4;
    const int ln15 = lane & 15;

#pragma unroll
    for (int p = 0; p < 4; ++p) {
        __syncthreads();
        if (!transpose) {
            if (wm == ((p >> 1) << 6)) {
#pragma unroll
                for (int ih = 0; ih < 2; ++ih) {
                    const int i = ((p & 1) << 1) + ih;
                    const int lr = ih * 16 + quad * 4;
#pragma unroll
                    for (int r = 0; r < 4; ++r) {
                        const int lm = wm + ((p & 1) << 5) + lr + r;
                        float ps = 0.f;
#pragma unroll
                        for (int j = 0; j < 4; ++j) {
                            const int ln = wn + j * 16 + ln15;
                            float v = acc[i][j][r] * scale;
                            if (expMask) {
                                v = (!diag || ln <= lm) ? __expf(v) : 0.f;
                            }
                            const __bf16 vb = (__bf16)v;
                            scratch[(lr + r) * 136 + ln] = vb;
                            ps += (float)vb;
                        }
                        if (sums) {
#pragma unroll
                            for (int off = 1; off < 16; off <<= 1)
                                ps += __shfl_xor(ps, off);
                            if (ln15 == 0)
                                atomicAdd(&sums[r0 + (p << 5) + lr + r], ps);
                        }
                    }
                }
            }
        } else {
            if (wn == ((p >> 1) << 6)) {
#pragma unroll
                for (int jh = 0; jh < 2; ++jh) {
                    const int j = ((p & 1) << 1) + jh;
                    const int lr = jh * 16 + ln15;
#pragma unroll
                    for (int i = 0; i < 4; ++i)
#pragma unroll
                        for (int r = 0; r < 4; ++r)
                            scratch[lr * 136 + wm + i * 16 + quad * 4 + r] =
                                (__bf16)(acc[i][j][r] * scale);
                }
            }
        }
        __syncthreads();
#pragma unroll
        for (int it = 0; it < 2; ++it) {
            const int g   = tid + (it << 8);
            const int row = g >> 4;
            const int col = (g & 15) << 3;
            *(bf16x8*)(dst + (r0 + p * 32 + row) * ldo + c0 + col) =
                *(const bf16x8*)(scratch + row * 136 + col);
        }
    }
}

// ---------------------------------------------------------------------------
// K1: QKV — 1536 single-unit blocks (one 128x128 unit each; 64 x-panels x 24
// W-units). Wall = contiguous [3072][1024] bf16. 4 blocks/CU -> capacity
// 1024 resident + 512 trailing. Bijective XCD swizzle (1536 = 8*192): XCD c
// owns x-panels [8c, 8c+8) (2 MB, L2-resident).
__global__ __launch_bounds__(256, 4) void qkv_kernel(
    const __bf16* __restrict__ x,
    const __bf16* __restrict__ Wall,
    __bf16* __restrict__ Q, __bf16* __restrict__ Kb, __bf16* __restrict__ Vt)
{
    __shared__ __bf16 smem[16384];   // 32 KiB

    const int L  = blockIdx.x;
    const int g  = (L & 7) * 192 + (L >> 3);  // 0..1535
    const int m0 = (g / 24) << 7;             // 64 m-panels of 128 rows
    const int u  = g % 24;                    // W-unit over Wall's 3072 rows

    const __bf16* Ab = x + (size_t)m0 * DIM;

    f32x4 acc[4][4];
    unit128(Ab, DIM, Wall + (size_t)(u << 7) * DIM, DIM, DIM / 64, smem, acc);

    const int z  = u >> 3;                    // 0=Q, 1=K, 2=V
    const int n0 = (u & 7) << 7;
    if (z == 0) {
        store_tile_bf16(acc, smem, false, 1.f, Q,  DIM, m0, n0);
    } else if (z == 1) {
        store_tile_bf16(acc, smem, false, 1.f, Kb, DIM, m0, n0);
    } else {
        const size_t b  = (size_t)(m0 >> 11);
        const int  ms0  = m0 & (SEQ - 1);
        store_tile_bf16(acc, smem, true, 1.f,
                        Vt + b * (size_t)DIM * SEQ, SEQ, n0, ms0);
    }
}

// ---------------------------------------------------------------------------
// K2: Sc[b] = exp( Q[b]·K[b]^T / 32 ), UNNORMALIZED, causal-masked on the
// diagonal tile; accumulates per-row sums. Tri-packed 544 blocks; XCD
// swizzle. At 4 blocks/CU all 544 are co-resident -> single round.
__global__ __launch_bounds__(256, 4) void scores_kernel(
    const __bf16* __restrict__ Q, const __bf16* __restrict__ Kb,
    __bf16* __restrict__ Sc, float* __restrict__ sums)
{
    __shared__ __bf16 smem[16384];   // 32 KiB

    const int L = blockIdx.x;
    const int g = (L & 7) * 68 + (L >> 3);   // 0..543
    const int b = g / 136;
    const int t = g - b * 136;
    int i = (int)((sqrtf(8.f * t + 1.f) - 1.f) * 0.5f);
    while ((i + 1) * (i + 2) / 2 <= t) ++i;
    while (i * (i + 1) / 2 > t) --i;
    const int j = t - i * (i + 1) / 2;

    const __bf16* A  = Q  + (size_t)b * SEQ * DIM + (size_t)(i << 7) * DIM;
    const __bf16* Bm = Kb + (size_t)b * SEQ * DIM + (size_t)(j << 7) * DIM;

    f32x4 acc[4][4];
    unit128(A, DIM, Bm, DIM, DIM / 64, smem, acc);

    store_tile_bf16(acc, smem, false, 0.03125f,   // 1/sqrt(1024)
                    Sc + (size_t)b * SEQ * SEQ, SEQ,
                    (size_t)(i << 7), (size_t)(j << 7),
                    /*expMask=*/true, /*diag=*/(i == j),
                    sums + (size_t)b * SEQ);
}

// ---------------------------------------------------------------------------
// K4: O[b] = (P'[b] @ V[b]) / rowsum. 512 blocks, all co-resident at 4/CU:
// unit = 128 P-rows (ti) x 128 V-cols (dj), K = (ti+1)*128 to the causal
// diagonal (tiles above diagonal never read). XCD c owns batch c>>1 with
// alternating-ti set, ti-descending (LPT).
__global__ __launch_bounds__(256, 4) void pv_kernel(
    const __bf16* __restrict__ P, const __bf16* __restrict__ Vt,
    const float* __restrict__ sums, float* __restrict__ out)
{
    __shared__ __bf16 smem[16384];   // 32 KiB

    const int L   = blockIdx.x;
    const int c   = L & 7;
    const int idx = L >> 3;                        // 0..63
    const int b   = c >> 1;
    const int ti  = 15 - (c & 1) - ((idx >> 3) << 1);  // {15,13,..,1}/{14,..,0}
    const int dj  = idx & 7;

    const __bf16* A  = P  + (size_t)b * SEQ * SEQ + (size_t)(ti << 7) * SEQ;
    const __bf16* Bm = Vt + (size_t)b * DIM * SEQ + (size_t)(dj << 7) * SEQ;

    f32x4 acc[4][4];
    unit128(A, SEQ, Bm, SEQ, (ti + 1) * 2, smem, acc);

    const int tid  = threadIdx.x;
    const int lane = tid & 63;
    const int ln15 = lane & 15;
    const int quad = lane >> 4;
    const int wave = tid >> 6;
    const int wm   = (wave >> 1) << 6;
    const int wn   = (wave & 1) << 6;

#pragma unroll
    for (int i = 0; i < 4; ++i)
#pragma unroll
        for (int r = 0; r < 4; ++r) {
            const int m = (ti << 7) + wm + i * 16 + quad * 4 + r;
            const float s = sums[(b << 11) + m];
            float* orow = out + ((size_t)b * SEQ + m) * DIM + (dj << 7);
#pragma unroll
            for (int j = 0; j < 4; ++j)
                orow[wn + j * 16 + ln15] = acc[i][j][r] / s;
        }
}

// ---------------------------------------------------------------------------
extern "C" void kernel_launch(void* const* d_in, const int* in_sizes, int n_in,
                              void* d_out, int out_size, void* d_ws, size_t ws_size,
                              hipStream_t stream) {
    const float* x  = (const float*)d_in[0];   // fp32 per reference
    const float* Wq = (const float*)d_in[1];
    const float* Wk = (const float*)d_in[2];
    const float* Wv = (const float*)d_in[3];
    float* out = (float*)d_out;                // fp32 output (reference dtype)

    char* ws = (char*)d_ws;
    __bf16* Q  = (__bf16*)(ws);                       // 16 MB
    __bf16* Kb = (__bf16*)(ws + (16ull << 20));       // 16 MB
    __bf16* Vt = (__bf16*)(ws + (32ull << 20));       // 16 MB
    __bf16* Sc = (__bf16*)(ws + (48ull << 20));       // 32 MB bf16 exp-scores
    __bf16* Wqb = (__bf16*)(ws + (80ull << 20));      // 2 MB (Wall rows 0..1023)
    __bf16* Wkb = (__bf16*)(ws + (82ull << 20));      // 2 MB (Wall rows 1024..2047)
    __bf16* Wvb = (__bf16*)(ws + (84ull << 20));      // 2 MB (Wall rows 2048..3071)
    float*  sums = (float*)(ws + (86ull << 20));      // 32 KB row sums
    // bf16 x copy lives in d_out (32 MB fp32): dead before pv writes out.
    __bf16* xb  = (__bf16*)d_out;                     // 16 MB

    cvt_all_kernel<<<dim3(5640), 256, 0, stream>>>(x, Wq, Wk, Wv, xb, Wqb, Wkb, Wvb,
                                                   sums);

    qkv_kernel    <<<dim3(1536), 256, 0, stream>>>(xb, Wqb, Q, Kb, Vt);
    scores_kernel <<<dim3(544),  256, 0, stream>>>(Q, Kb, Sc, sums);
    pv_kernel     <<<dim3(512),  256, 0, stream>>>(Sc, Vt, sums, out);
}

// Round 14
// 225.812 us; speedup vs baseline: 4.7935x; 1.7004x over previous
//
#include <hip/hip_runtime.h>

// Problem constants
#define BATCH 4
#define SEQ   2048
#define DIM   1024
#define MTOT  (BATCH * SEQ)   // 8192

typedef __bf16 bf16x8 __attribute__((ext_vector_type(8)));
typedef float  f32x4  __attribute__((ext_vector_type(4)));

#define VMCNT(N) asm volatile("s_waitcnt vmcnt(" #N ")" ::: "memory")

// Async global->LDS, 16B per lane (HW: wave-uniform base + lane*16).
__device__ __forceinline__ void gl_lds16(const __bf16* g, __bf16* l) {
    __builtin_amdgcn_global_load_lds(
        (const __attribute__((address_space(1))) void*)g,
        (__attribute__((address_space(3))) void*)l,
        16, 0, 0);
}

// ---------------------------------------------------------------------------
// K0: fused fp32 -> bf16 conversion for x, Wq, Wk, Wv in ONE launch.
// Blocks 5632..5639 zero the row-sum accumulator (8192 f32).
__global__ __launch_bounds__(256) void cvt_all_kernel(
    const float* __restrict__ x,  const float* __restrict__ w0,
    const float* __restrict__ w1, const float* __restrict__ w2,
    __bf16* __restrict__ xd, __bf16* __restrict__ d0,
    __bf16* __restrict__ d1, __bf16* __restrict__ d2,
    float* __restrict__ sums)
{
    const int bid = blockIdx.x;
    if (bid >= 5632) {
        const int i = ((bid - 5632) * 256 + threadIdx.x) * 4;
        *(float4*)(sums + i) = (float4){0.f, 0.f, 0.f, 0.f};
        return;
    }
    const float* s;
    __bf16* d;
    int base;
    if (bid < 4096)      { s = x;  d = xd; base = bid; }
    else if (bid < 4608) { s = w0; d = d0; base = bid - 4096; }
    else if (bid < 5120) { s = w1; d = d1; base = bid - 4608; }
    else                 { s = w2; d = d2; base = bid - 5120; }
    const int i = (base * 256 + threadIdx.x) * 8;
    const float4 a = *(const float4*)(s + i);
    const float4 b = *(const float4*)(s + i + 4);
    bf16x8 o;
    o[0] = (__bf16)a.x; o[1] = (__bf16)a.y; o[2] = (__bf16)a.z; o[3] = (__bf16)a.w;
    o[4] = (__bf16)b.x; o[5] = (__bf16)b.y; o[6] = (__bf16)b.z; o[7] = (__bf16)b.w;
    *(bf16x8*)(d + i) = o;
}

// ---------------------------------------------------------------------------
// unit128 (BK=64, SINGLE-buffered, ks-split, register-slim): C[128][128] =
// A[128][K]·B[128][K]^T, 256 threads (4 waves), wave grid 2M x 2N (wave
// 64x64, acc[4][4], legacy fragment mapping: rows wm + i*16 + quad*4 + r,
// cols wn + j*16 + ln15).
// LDS 32 KiB: A[128][64] @0 + B[128][64] @8192 elems (ONE buffer).
// OCCUPANCY MATH (r12/r13 LESSON): kernel footprint = 64 AGPR (acc) +
// arch VGPRs. Old 16-frag live set needed ~176 total -> spilled at caps
// 128 (256,4) and 102 (256,5); scratch traffic 10x'd HBM bytes. This
// version keeps only 8 frags live (aF[4]+bF[4] = 32 VGPR) via two ks
// passes per K-tile, sched_barrier(0) between them so the compiler can't
// hoist the ks=1 reads and re-inflate pressure. Total ~140 <= 168 cap at
// __launch_bounds__(256,3) -> 3 blocks/CU, 3 independent barrier domains
// overlapping MFMA with staging (m114).
// Per K-tile: {8 ds_read ks0 + 16 MFMA} {8 ds_read ks1 + 16 MFMA} ->
// syncthreads -> STG(T+1) + vmcnt(0) -> syncthreads.
// Rotation swizzle (mod 8, proven r2..r9, 327K residual conflicts):
// LDS[r][pc] holds G[r][(pc - r) & 7] (8-elem chunks); inverse rotation on
// the gl_lds global source column, forward rotation on the ds_read address;
// ksub1 address = ksub0 ^ 32 elems (chunk+4 mod 8).
__device__ __forceinline__ void unit128(
    const __bf16* __restrict__ Ab, size_t lda,
    const __bf16* __restrict__ Bb, size_t ldb,
    int nt, __bf16* smem, f32x4 (&acc)[4][4])
{
    const int tid  = threadIdx.x;           // 0..255
    const int lane = tid & 63;
    const int ln15 = lane & 15;
    const int quad = lane >> 4;
    const int wave = tid >> 6;              // 0..3
    const int wm   = (wave >> 1) << 6;      // 0 / 64
    const int wn   = (wave & 1) << 6;       // 0 / 64

    // forward-rotated read column (elements): chunk = (quad + row&7) & 7
    const int cq = (((quad << 3) + ((ln15 & 7) << 3)) & 63);

    int aoff[4], boff[4];
#pragma unroll
    for (int i = 0; i < 4; ++i) aoff[i] = (wm + i * 16 + ln15) * 64 + cq;
#pragma unroll
    for (int j = 0; j < 4; ++j) boff[j] = 8192 + (wn + j * 16 + ln15) * 64 + cq;

#pragma unroll
    for (int i = 0; i < 4; ++i)
#pragma unroll
        for (int j = 0; j < 4; ++j) acc[i][j] = (f32x4){0.f, 0.f, 0.f, 0.f};

    // Stage tile t: thread covers chunks c = tid + it*256 (row=c>>3, pc=c&7);
    // source chunk = (pc - row) & 7 (inverse rotation); LDS dest linear.
#define STG(t) do {                                                           \
    const int k0_ = (t) << 6;                                                 \
    _Pragma("unroll") for (int it_ = 0; it_ < 4; ++it_) {                     \
        const int c_ = tid + (it_ << 8);                                      \
        const int r_ = c_ >> 3;                                               \
        const int cc_ = ((((c_ & 7) + 8) - (r_ & 7)) & 7) << 3;               \
        gl_lds16(Ab + (size_t)r_ * lda + k0_ + cc_, smem + c_ * 8);           \
        gl_lds16(Bb + (size_t)r_ * ldb + k0_ + cc_, smem + 8192 + c_ * 8);    \
    } } while (0)

    bf16x8 aF[4], bF[4];

    STG(0);
    VMCNT(0);                                // tile 0 sealed
    __syncthreads();

    for (int T = 0; T < nt; ++T) {
        // ---- ks = 0 ----
#pragma unroll
        for (int i = 0; i < 4; ++i) aF[i] = *(const bf16x8*)(smem + aoff[i]);
#pragma unroll
        for (int j = 0; j < 4; ++j) bF[j] = *(const bf16x8*)(smem + boff[j]);
        __builtin_amdgcn_s_setprio(1);
#pragma unroll
        for (int i = 0; i < 4; ++i)
#pragma unroll
            for (int j = 0; j < 4; ++j)
                acc[i][j] = __builtin_amdgcn_mfma_f32_16x16x32_bf16(
                    aF[i], bF[j], acc[i][j], 0, 0, 0);
        __builtin_amdgcn_s_setprio(0);
        __builtin_amdgcn_sched_barrier(0);   // pin ks=1 reads AFTER ks=0 MFMAs
        // ---- ks = 1 (reuse the same 8 frag registers) ----
#pragma unroll
        for (int i = 0; i < 4; ++i) aF[i] = *(const bf16x8*)(smem + (aoff[i] ^ 32));
#pragma unroll
        for (int j = 0; j < 4; ++j) bF[j] = *(const bf16x8*)(smem + (boff[j] ^ 32));
        __builtin_amdgcn_s_setprio(1);
#pragma unroll
        for (int i = 0; i < 4; ++i)
#pragma unroll
            for (int j = 0; j < 4; ++j)
                acc[i][j] = __builtin_amdgcn_mfma_f32_16x16x32_bf16(
                    aF[i], bF[j], acc[i][j], 0, 0, 0);
        __builtin_amdgcn_s_setprio(0);
        __syncthreads();                     // all waves' reads consumed
        if (T + 1 < nt) {
            STG(T + 1);                      // overwrite the single buffer
            VMCNT(0);                        // sealed (this wave's 8 stages)
            __syncthreads();                 // sealed for ALL waves
        }
    }
#undef STG
}

// ---------------------------------------------------------------------------
// Epilogue (256-thr, 4-wave, legacy mapping): C-tile -> LDS scratch (32x136)
// -> coalesced bf16x8 stores. expMask: store exp(val*scale), causal-masked on
// diag tiles. sums!=nullptr: per-row sums of stored (bf16-rounded) values.
__device__ __forceinline__ void store_tile_bf16(
    f32x4 (&acc)[4][4], __bf16* scratch, bool transpose, float scale,
    __bf16* dst, size_t ldo, size_t r0, size_t c0,
    bool expMask = false, bool diag = false, float* sums = nullptr)
{
    const int tid  = threadIdx.x;
    const int lane = tid & 63;
    const int wave = tid >> 6;
    const int wm = (wave >> 1) << 6, wn = (wave & 1) << 6;
    const int quad = lane >> 4;
    const int ln15 = lane & 15;

#pragma unroll
    for (int p = 0; p < 4; ++p) {
        __syncthreads();
        if (!transpose) {
            if (wm == ((p >> 1) << 6)) {
#pragma unroll
                for (int ih = 0; ih < 2; ++ih) {
                    const int i = ((p & 1) << 1) + ih;
                    const int lr = ih * 16 + quad * 4;
#pragma unroll
                    for (int r = 0; r < 4; ++r) {
                        const int lm = wm + ((p & 1) << 5) + lr + r;
                        float ps = 0.f;
#pragma unroll
                        for (int j = 0; j < 4; ++j) {
                            const int ln = wn + j * 16 + ln15;
                            float v = acc[i][j][r] * scale;
                            if (expMask) {
                                v = (!diag || ln <= lm) ? __expf(v) : 0.f;
                            }
                            const __bf16 vb = (__bf16)v;
                            scratch[(lr + r) * 136 + ln] = vb;
                            ps += (float)vb;
                        }
                        if (sums) {
#pragma unroll
                            for (int off = 1; off < 16; off <<= 1)
                                ps += __shfl_xor(ps, off);
                            if (ln15 == 0)
                                atomicAdd(&sums[r0 + (p << 5) + lr + r], ps);
                        }
                    }
                }
            }
        } else {
            if (wn == ((p >> 1) << 6)) {
#pragma unroll
                for (int jh = 0; jh < 2; ++jh) {
                    const int j = ((p & 1) << 1) + jh;
                    const int lr = jh * 16 + ln15;
#pragma unroll
                    for (int i = 0; i < 4; ++i)
#pragma unroll
                        for (int r = 0; r < 4; ++r)
                            scratch[lr * 136 + wm + i * 16 + quad * 4 + r] =
                                (__bf16)(acc[i][j][r] * scale);
                }
            }
        }
        __syncthreads();
#pragma unroll
        for (int it = 0; it < 2; ++it) {
            const int g   = tid + (it << 8);
            const int row = g >> 4;
            const int col = (g & 15) << 3;
            *(bf16x8*)(dst + (r0 + p * 32 + row) * ldo + c0 + col) =
                *(const bf16x8*)(scratch + row * 136 + col);
        }
    }
}

// ---------------------------------------------------------------------------
// K1: QKV — 768 blocks x 2 sequential 128x128 units (shared 128-row x-panel;
// 64 panels x 12 unit-pairs). Wall = contiguous [3072][1024] bf16.
// Exact 1 dispatch round at 3 blocks/CU (capacity 768). Bijective XCD
// swizzle (768 = 8*96): XCD c owns panels [8c, 8c+8) -> each 256 KB x-panel
// stays in its XCD's L2 across its 12 pair-blocks.
__global__ __launch_bounds__(256, 3) void qkv_kernel(
    const __bf16* __restrict__ x,
    const __bf16* __restrict__ Wall,
    __bf16* __restrict__ Q, __bf16* __restrict__ Kb, __bf16* __restrict__ Vt)
{
    __shared__ __bf16 smem[16384];   // 32 KiB

    const int L  = blockIdx.x;
    const int g  = (L & 7) * 96 + (L >> 3);   // 0..767
    const int m0 = (g / 12) << 7;             // 64 m-panels of 128 rows
    const int pr = g % 12;                    // unit-pair within the panel

    const __bf16* Ab = x + (size_t)m0 * DIM;

    for (int uu = 0; uu < 2; ++uu) {
        const int u = pr * 2 + uu;            // 0..23 over Wall's 3072 rows
        f32x4 acc[4][4];
        unit128(Ab, DIM, Wall + (size_t)(u << 7) * DIM, DIM, DIM / 64,
                smem, acc);

        const int z  = u >> 3;                // 0=Q, 1=K, 2=V
        const int n0 = (u & 7) << 7;
        if (z == 0) {
            store_tile_bf16(acc, smem, false, 1.f, Q,  DIM, m0, n0);
        } else if (z == 1) {
            store_tile_bf16(acc, smem, false, 1.f, Kb, DIM, m0, n0);
        } else {
            const size_t b  = (size_t)(m0 >> 11);
            const int  ms0  = m0 & (SEQ - 1);
            store_tile_bf16(acc, smem, true, 1.f,
                            Vt + b * (size_t)DIM * SEQ, SEQ, n0, ms0);
        }
        __syncthreads();
    }
}

// ---------------------------------------------------------------------------
// K2: Sc[b] = exp( Q[b]·K[b]^T / 32 ), UNNORMALIZED, causal-masked on the
// diagonal tile; accumulates per-row sums. Tri-packed 544 blocks; XCD
// swizzle. At 3 blocks/CU (capacity 768) all 544 co-resident -> one round.
__global__ __launch_bounds__(256, 3) void scores_kernel(
    const __bf16* __restrict__ Q, const __bf16* __restrict__ Kb,
    __bf16* __restrict__ Sc, float* __restrict__ sums)
{
    __shared__ __bf16 smem[16384];   // 32 KiB

    const int L = blockIdx.x;
    const int g = (L & 7) * 68 + (L >> 3);   // 0..543
    const int b = g / 136;
    const int t = g - b * 136;
    int i = (int)((sqrtf(8.f * t + 1.f) - 1.f) * 0.5f);
    while ((i + 1) * (i + 2) / 2 <= t) ++i;
    while (i * (i + 1) / 2 > t) --i;
    const int j = t - i * (i + 1) / 2;

    const __bf16* A  = Q  + (size_t)b * SEQ * DIM + (size_t)(i << 7) * DIM;
    const __bf16* Bm = Kb + (size_t)b * SEQ * DIM + (size_t)(j << 7) * DIM;

    f32x4 acc[4][4];
    unit128(A, DIM, Bm, DIM, DIM / 64, smem, acc);

    store_tile_bf16(acc, smem, false, 0.03125f,   // 1/sqrt(1024)
                    Sc + (size_t)b * SEQ * SEQ, SEQ,
                    (size_t)(i << 7), (size_t)(j << 7),
                    /*expMask=*/true, /*diag=*/(i == j),
                    sums + (size_t)b * SEQ);
}

// ---------------------------------------------------------------------------
// K4: O[b] = (P'[b] @ V[b]) / rowsum. 512 blocks, all co-resident at 3/CU:
// unit = 128 P-rows (ti) x 128 V-cols (dj), K = (ti+1)*128 to the causal
// diagonal (tiles above diagonal never read). XCD c owns batch c>>1 with
// alternating-ti set, ti-descending (LPT).
__global__ __launch_bounds__(256, 3) void pv_kernel(
    const __bf16* __restrict__ P, const __bf16* __restrict__ Vt,
    const float* __restrict__ sums, float* __restrict__ out)
{
    __shared__ __bf16 smem[16384];   // 32 KiB

    const int L   = blockIdx.x;
    const int c   = L & 7;
    const int idx = L >> 3;                        // 0..63
    const int b   = c >> 1;
    const int ti  = 15 - (c & 1) - ((idx >> 3) << 1);  // {15,13,..,1}/{14,..,0}
    const int dj  = idx & 7;

    const __bf16* A  = P  + (size_t)b * SEQ * SEQ + (size_t)(ti << 7) * SEQ;
    const __bf16* Bm = Vt + (size_t)b * DIM * SEQ + (size_t)(dj << 7) * SEQ;

    f32x4 acc[4][4];
    unit128(A, SEQ, Bm, SEQ, (ti + 1) * 2, smem, acc);

    const int tid  = threadIdx.x;
    const int lane = tid & 63;
    const int ln15 = lane & 15;
    const int quad = lane >> 4;
    const int wave = tid >> 6;
    const int wm   = (wave >> 1) << 6;
    const int wn   = (wave & 1) << 6;

#pragma unroll
    for (int i = 0; i < 4; ++i)
#pragma unroll
        for (int r = 0; r < 4; ++r) {
            const int m = (ti << 7) + wm + i * 16 + quad * 4 + r;
            const float s = sums[(b << 11) + m];
            float* orow = out + ((size_t)b * SEQ + m) * DIM + (dj << 7);
#pragma unroll
            for (int j = 0; j < 4; ++j)
                orow[wn + j * 16 + ln15] = acc[i][j][r] / s;
        }
}

// ---------------------------------------------------------------------------
extern "C" void kernel_launch(void* const* d_in, const int* in_sizes, int n_in,
                              void* d_out, int out_size, void* d_ws, size_t ws_size,
                              hipStream_t stream) {
    const float* x  = (const float*)d_in[0];   // fp32 per reference
    const float* Wq = (const float*)d_in[1];
    const float* Wk = (const float*)d_in[2];
    const float* Wv = (const float*)d_in[3];
    float* out = (float*)d_out;                // fp32 output (reference dtype)

    char* ws = (char*)d_ws;
    __bf16* Q  = (__bf16*)(ws);                       // 16 MB
    __bf16* Kb = (__bf16*)(ws + (16ull << 20));       // 16 MB
    __bf16* Vt = (__bf16*)(ws + (32ull << 20));       // 16 MB
    __bf16* Sc = (__bf16*)(ws + (48ull << 20));       // 32 MB bf16 exp-scores
    __bf16* Wqb = (__bf16*)(ws + (80ull << 20));      // 2 MB (Wall rows 0..1023)
    __bf16* Wkb = (__bf16*)(ws + (82ull << 20));      // 2 MB (Wall rows 1024..2047)
    __bf16* Wvb = (__bf16*)(ws + (84ull << 20));      // 2 MB (Wall rows 2048..3071)
    float*  sums = (float*)(ws + (86ull << 20));      // 32 KB row sums
    // bf16 x copy lives in d_out (32 MB fp32): dead before pv writes out.
    __bf16* xb  = (__bf16*)d_out;                     // 16 MB

    cvt_all_kernel<<<dim3(5640), 256, 0, stream>>>(x, Wq, Wk, Wv, xb, Wqb, Wkb, Wvb,
                                                   sums);

    qkv_kernel    <<<dim3(768),  256, 0, stream>>>(xb, Wqb, Q, Kb, Vt);
    scores_kernel <<<dim3(544),  256, 0, stream>>>(Q, Kb, Sc, sums);
    pv_kernel     <<<dim3(512),  256, 0, stream>>>(Sc, Vt, sums, out);
}